// Round 1
// baseline (731.472 us; speedup 1.0000x reference)
//
#include <hip/hip_runtime.h>
#include <hip/hip_bf16.h>

typedef __bf16 bf16x8 __attribute__((ext_vector_type(8)));
typedef float f32x4 __attribute__((ext_vector_type(4)));

#define DEV static __device__ __forceinline__

DEV unsigned short f2bf(float x) {
  union { __hip_bfloat16 b; unsigned short u; } c;
  c.b = __float2bfloat16(x);
  return c.u;
}

DEV void gload_lds16(const void* g, void* l) {
  __builtin_amdgcn_global_load_lds((const __attribute__((address_space(1))) void*)g,
                                   (__attribute__((address_space(3))) void*)l, 16, 0, 0);
}

// ---------- convert q/k/v fp32 -> bf16 ----------
__global__ __launch_bounds__(256) void cvt_qkv(const float* __restrict__ q,
                                               const float* __restrict__ k,
                                               const float* __restrict__ v,
                                               unsigned short* __restrict__ qb,
                                               unsigned short* __restrict__ kb,
                                               unsigned short* __restrict__ vb) {
  const float* src = blockIdx.y == 0 ? q : (blockIdx.y == 1 ? k : v);
  unsigned short* dst = blockIdx.y == 0 ? qb : (blockIdx.y == 1 ? kb : vb);
  int idx = (blockIdx.x * 256 + threadIdx.x) * 4;
  float4 xv = *(const float4*)(src + idx);
  ushort4 o;
  o.x = f2bf(xv.x); o.y = f2bf(xv.y); o.z = f2bf(xv.z); o.w = f2bf(xv.w);
  *(ushort4*)(dst + idx) = o;
}

// ---------- transpose 1024x1024 weight fp32 -> bf16 (Wt[n][k] = W[k][n]) ----------
__global__ __launch_bounds__(256) void transpose_w(const float* __restrict__ W,
                                                   unsigned short* __restrict__ Wt) {
  __shared__ float t[64][68];
  int tile = blockIdx.x; int tr = tile >> 4, tc = tile & 15;
  int lr = threadIdx.x >> 4, lc4 = threadIdx.x & 15;
#pragma unroll
  for (int i = 0; i < 4; ++i) {
    int r = i * 16 + lr;
    float4 v = *(const float4*)(W + (size_t)(tr * 64 + r) * 1024 + tc * 64 + lc4 * 4);
    t[r][lc4 * 4 + 0] = v.x; t[r][lc4 * 4 + 1] = v.y;
    t[r][lc4 * 4 + 2] = v.z; t[r][lc4 * 4 + 3] = v.w;
  }
  __syncthreads();
#pragma unroll
  for (int i = 0; i < 4; ++i) {
    int r = i * 16 + lr;   // n-local
    ushort4 o;
    o.x = f2bf(t[lc4 * 4 + 0][r]);
    o.y = f2bf(t[lc4 * 4 + 1][r]);
    o.z = f2bf(t[lc4 * 4 + 2][r]);
    o.w = f2bf(t[lc4 * 4 + 3][r]);
    *(ushort4*)(Wt + (size_t)(tc * 64 + r) * 1024 + tr * 64 + lc4 * 4) = o;
  }
}

// ---------- GEMM: C[4096,1024] = A[4096,1024] @ Bt[1024,1024]^T + bias, then *scale ----------
// MODE 0: bf16 out, head layout [B,H,S,64]   (Q, K)
// MODE 1: bf16 out, head-T layout [B,H,64,S] (V)
// MODE 2: fp32 out, row-major [4096,1024]    (final)
template<int MODE>
__global__ __launch_bounds__(256) void gemm_bt(const unsigned short* __restrict__ A,
                                               const unsigned short* __restrict__ Bt,
                                               const float* __restrict__ bias,
                                               void* __restrict__ Cout,
                                               float scale) {
  __shared__ unsigned short As[128 * 64];
  __shared__ unsigned short Bs[128 * 64];
  const int tid = threadIdx.x;
  const int l = tid & 63, w = tid >> 6;
  const int wm = w >> 1, wn = w & 1;
  const int r15 = l & 15, kg = l >> 4;
  const int mt = blockIdx.x >> 3, nt = blockIdx.x & 7;

  const f32x4 fzero = {0.f, 0.f, 0.f, 0.f};
  f32x4 acc[4][4];
#pragma unroll
  for (int i = 0; i < 4; ++i)
#pragma unroll
    for (int j = 0; j < 4; ++j) acc[i][j] = fzero;

  for (int kt = 0; kt < 16; ++kt) {
#pragma unroll
    for (int c = 0; c < 4; ++c) {
      int chunk = c * 256 + tid;
      int row = chunk >> 3, slot = chunk & 7;
      int gsl = slot ^ (row & 7);   // source pre-swizzle (LDS dest stays linear)
      gload_lds16(A + (size_t)(mt * 128 + row) * 1024 + kt * 64 + gsl * 8, As + chunk * 8);
      gload_lds16(Bt + (size_t)(nt * 128 + row) * 1024 + kt * 64 + gsl * 8, Bs + chunk * 8);
    }
    __syncthreads();
#pragma unroll
    for (int ks = 0; ks < 2; ++ks) {
      bf16x8 a[4], b[4];
      int slot = ks * 4 + kg;
#pragma unroll
      for (int i = 0; i < 4; ++i) {
        int ra = wm * 64 + i * 16 + r15;
        a[i] = *(const bf16x8*)(As + ra * 64 + (slot ^ (ra & 7)) * 8);
        int rb = wn * 64 + i * 16 + r15;
        b[i] = *(const bf16x8*)(Bs + rb * 64 + (slot ^ (rb & 7)) * 8);
      }
#pragma unroll
      for (int i = 0; i < 4; ++i)
#pragma unroll
        for (int j = 0; j < 4; ++j)
          acc[i][j] = __builtin_amdgcn_mfma_f32_16x16x32_bf16(a[i], b[j], acc[i][j], 0, 0, 0);
    }
    __syncthreads();
  }

#pragma unroll
  for (int j = 0; j < 4; ++j) {
    int gc = nt * 128 + wn * 64 + j * 16 + r15;
    float bj = bias[gc];
#pragma unroll
    for (int i = 0; i < 4; ++i) {
#pragma unroll
      for (int r = 0; r < 4; ++r) {
        int gr = mt * 128 + wm * 64 + i * 16 + kg * 4 + r;
        float val = (acc[i][j][r] + bj) * scale;
        if (MODE == 2) {
          ((float*)Cout)[(size_t)gr * 1024 + gc] = val;
        } else {
          int bb = gr >> 11, s = gr & 2047, hh = gc >> 6, dk = gc & 63;
          if (MODE == 0)
            ((unsigned short*)Cout)[((size_t)(bb * 16 + hh) * 2048 + s) * 64 + dk] = f2bf(val);
          else
            ((unsigned short*)Cout)[((size_t)(bb * 16 + hh) * 64 + dk) * 2048 + s] = f2bf(val);
        }
      }
    }
  }
}

// ---------- attention: per wg = (b,h, 16 q-rows): scores, softmax, attn write, PV ----------
__global__ __launch_bounds__(256) void attn_kernel(const unsigned short* __restrict__ Qh,
                                                   const unsigned short* __restrict__ Kh,
                                                   const unsigned short* __restrict__ Vt,
                                                   float* __restrict__ attnO,
                                                   unsigned short* __restrict__ AO) {
  __shared__ float Srow[16][2052];          // padded: +4 floats -> <=2-way conflicts
  __shared__ unsigned short Kbuf[2][4096];  // 64x64 bf16, double-buffered
  __shared__ float mrow[16], rrow[16];

  const int tid = threadIdx.x;
  const int l = tid & 63, w = tid >> 6;
  const int r15 = l & 15, kg = l >> 4;
  const int qt = blockIdx.x & 127;
  const int h = (blockIdx.x >> 7) & 15;
  const int b = blockIdx.x >> 11;
  const int bh = b * 16 + h;
  const int q0 = qt * 16;

  // Q fragments (Q is pre-scaled by 1/8)
  const unsigned short* Qp = Qh + ((size_t)bh * 2048 + q0 + r15) * 64 + kg * 8;
  bf16x8 aq0 = *(const bf16x8*)(Qp);
  bf16x8 aq1 = *(const bf16x8*)(Qp + 32);

  const unsigned short* Kbase = Kh + (size_t)bh * 2048 * 64;

  // prologue: stage K tile 0
#pragma unroll
  for (int c = 0; c < 2; ++c) {
    int chunk = c * 256 + tid;
    int row = chunk >> 3, slot = chunk & 7;
    gload_lds16(Kbase + (size_t)row * 64 + (slot ^ (row & 7)) * 8, &Kbuf[0][chunk * 8]);
  }

  // pass 1: scores into Srow
  for (int kt = 0; kt < 32; ++kt) {
    __syncthreads();
    if (kt < 31) {
      int ktn = kt + 1;
#pragma unroll
      for (int c = 0; c < 2; ++c) {
        int chunk = c * 256 + tid;
        int row = chunk >> 3, slot = chunk & 7;
        gload_lds16(Kbase + (size_t)(ktn * 64 + row) * 64 + (slot ^ (row & 7)) * 8,
                    &Kbuf[ktn & 1][chunk * 8]);
      }
    }
    const unsigned short* kb_ = &Kbuf[kt & 1][0];
    int nloc = w * 16 + r15;
    bf16x8 b0 = *(const bf16x8*)(kb_ + nloc * 64 + ((kg ^ (nloc & 7)) * 8));
    bf16x8 b1 = *(const bf16x8*)(kb_ + nloc * 64 + (((4 + kg) ^ (nloc & 7)) * 8));
    f32x4 sc = {0.f, 0.f, 0.f, 0.f};
    sc = __builtin_amdgcn_mfma_f32_16x16x32_bf16(aq0, b0, sc, 0, 0, 0);
    sc = __builtin_amdgcn_mfma_f32_16x16x32_bf16(aq1, b1, sc, 0, 0, 0);
    int kcol = kt * 64 + nloc;
#pragma unroll
    for (int r = 0; r < 4; ++r) Srow[kg * 4 + r][kcol] = sc[r];
  }
  __syncthreads();

  // pass 2: row max + sumexp (16 lanes per row, shfl reduce)
  {
    int row = w * 4 + kg;
    float m = -1e30f;
    for (int i = 0; i < 32; ++i) {
      float4 sv = *(const float4*)&Srow[row][r15 * 4 + i * 64];
      m = fmaxf(m, fmaxf(fmaxf(sv.x, sv.y), fmaxf(sv.z, sv.w)));
    }
#pragma unroll
    for (int off = 1; off < 16; off <<= 1) m = fmaxf(m, __shfl_xor(m, off));
    float sum = 0.f;
    for (int i = 0; i < 32; ++i) {
      float4 sv = *(const float4*)&Srow[row][r15 * 4 + i * 64];
      sum += __expf(sv.x - m) + __expf(sv.y - m) + __expf(sv.z - m) + __expf(sv.w - m);
    }
#pragma unroll
    for (int off = 1; off < 16; off <<= 1) sum += __shfl_xor(sum, off);
    if (r15 == 0) { mrow[row] = m; rrow[row] = 1.0f / sum; }
  }
  __syncthreads();

  // pass 3: normalized attn -> global (coalesced float4)
  {
    float* attnBase = attnO + ((size_t)bh * 2048 + q0) * 2048;
    for (int it = 0; it < 32; ++it) {
      int flat = it * 256 + tid;
      int row = flat >> 9, c4 = flat & 511;
      float m = mrow[row], rv = rrow[row];
      float4 sv = *(const float4*)&Srow[row][c4 * 4];
      float4 ov;
      ov.x = __expf(sv.x - m) * rv;
      ov.y = __expf(sv.y - m) * rv;
      ov.z = __expf(sv.z - m) * rv;
      ov.w = __expf(sv.w - m) * rv;
      *(float4*)(attnBase + (size_t)row * 2048 + c4 * 4) = ov;
    }
  }

  // pass 4: PV via MFMA; wave w covers d-cols [16w,16w+16)
  {
    const unsigned short* Vh = Vt + (size_t)bh * 64 * 2048 + (size_t)(w * 16 + r15) * 2048;
    float m = mrow[r15], rv = rrow[r15];
    f32x4 oacc = {0.f, 0.f, 0.f, 0.f};
    for (int kt2 = 0; kt2 < 64; ++kt2) {
      int kb2 = kt2 * 32 + kg * 8;
      float4 s0 = *(const float4*)&Srow[r15][kb2];
      float4 s1 = *(const float4*)&Srow[r15][kb2 + 4];
      bf16x8 ap;
      ap[0] = (__bf16)(__expf(s0.x - m) * rv);
      ap[1] = (__bf16)(__expf(s0.y - m) * rv);
      ap[2] = (__bf16)(__expf(s0.z - m) * rv);
      ap[3] = (__bf16)(__expf(s0.w - m) * rv);
      ap[4] = (__bf16)(__expf(s1.x - m) * rv);
      ap[5] = (__bf16)(__expf(s1.y - m) * rv);
      ap[6] = (__bf16)(__expf(s1.z - m) * rv);
      ap[7] = (__bf16)(__expf(s1.w - m) * rv);
      bf16x8 bv2 = *(const bf16x8*)(Vh + kb2);
      oacc = __builtin_amdgcn_mfma_f32_16x16x32_bf16(ap, bv2, oacc, 0, 0, 0);
    }
#pragma unroll
    for (int r = 0; r < 4; ++r)
      AO[((size_t)(b * 2048 + q0 + kg * 4 + r)) * 1024 + h * 64 + w * 16 + r15] = f2bf(oacc[r]);
  }
}

extern "C" void kernel_launch(void* const* d_in, const int* in_sizes, int n_in,
                              void* d_out, int out_size, void* d_ws, size_t ws_size,
                              hipStream_t stream) {
  const float* q  = (const float*)d_in[0];
  const float* k  = (const float*)d_in[1];
  const float* v  = (const float*)d_in[2];
  const float* Wq = (const float*)d_in[3];
  const float* bq = (const float*)d_in[4];
  const float* Wk = (const float*)d_in[5];
  const float* bk = (const float*)d_in[6];
  const float* Wv = (const float*)d_in[7];
  const float* bvp = (const float*)d_in[8];
  const float* Wo = (const float*)d_in[9];
  const float* bo = (const float*)d_in[10];

  char* wsb = (char*)d_ws;
  const size_t MB = (size_t)1 << 20;
  unsigned short* qb  = (unsigned short*)(wsb + 0 * MB);
  unsigned short* kbp = (unsigned short*)(wsb + 8 * MB);
  unsigned short* vbp = (unsigned short*)(wsb + 16 * MB);
  unsigned short* Wtq = (unsigned short*)(wsb + 24 * MB);
  unsigned short* Wtk = (unsigned short*)(wsb + 26 * MB);
  unsigned short* Wtv = (unsigned short*)(wsb + 28 * MB);
  unsigned short* Wto = (unsigned short*)(wsb + 30 * MB);
  unsigned short* Qh  = (unsigned short*)(wsb + 32 * MB);
  unsigned short* Kh  = (unsigned short*)(wsb + 40 * MB);
  unsigned short* Vt  = (unsigned short*)(wsb + 48 * MB);
  unsigned short* AO  = (unsigned short*)(wsb + 56 * MB);

  float* out0 = (float*)d_out;
  float* attnO = out0 + (size_t)2 * 2048 * 1024;

  cvt_qkv<<<dim3(4096, 3), 256, 0, stream>>>(q, k, v, qb, kbp, vbp);
  transpose_w<<<256, 256, 0, stream>>>(Wq, Wtq);
  transpose_w<<<256, 256, 0, stream>>>(Wk, Wtk);
  transpose_w<<<256, 256, 0, stream>>>(Wv, Wtv);
  transpose_w<<<256, 256, 0, stream>>>(Wo, Wto);
  gemm_bt<0><<<256, 256, 0, stream>>>(qb, Wtq, bq, Qh, 0.125f);   // Q pre-scaled 1/sqrt(dk)
  gemm_bt<0><<<256, 256, 0, stream>>>(kbp, Wtk, bk, Kh, 1.0f);
  gemm_bt<1><<<256, 256, 0, stream>>>(vbp, Wtv, bvp, Vt, 1.0f);
  attn_kernel<<<4096, 256, 0, stream>>>(Qh, Kh, Vt, attnO, AO);
  gemm_bt<2><<<256, 256, 0, stream>>>(AO, Wto, bo, d_out, 1.0f);
}

// Round 2
// 386.686 us; speedup vs baseline: 1.8916x; 1.8916x over previous
//
#include <hip/hip_runtime.h>
#include <hip/hip_bf16.h>

typedef __bf16 bf16x8 __attribute__((ext_vector_type(8)));
typedef float f32x4 __attribute__((ext_vector_type(4)));

#define DEV static __device__ __forceinline__

DEV unsigned short f2bf(float x) {
  union { __hip_bfloat16 b; unsigned short u; } c;
  c.b = __float2bfloat16(x);
  return c.u;
}

DEV void gload_lds16(const void* g, void* l) {
  __builtin_amdgcn_global_load_lds((const __attribute__((address_space(1))) void*)g,
                                   (__attribute__((address_space(3))) void*)l, 16, 0, 0);
}

// ---------- convert q/k/v fp32 -> bf16 ----------
__global__ __launch_bounds__(256) void cvt_qkv(const float* __restrict__ q,
                                               const float* __restrict__ k,
                                               const float* __restrict__ v,
                                               unsigned short* __restrict__ qb,
                                               unsigned short* __restrict__ kb,
                                               unsigned short* __restrict__ vb) {
  const float* src = blockIdx.y == 0 ? q : (blockIdx.y == 1 ? k : v);
  unsigned short* dst = blockIdx.y == 0 ? qb : (blockIdx.y == 1 ? kb : vb);
  int idx = (blockIdx.x * 256 + threadIdx.x) * 4;
  float4 xv = *(const float4*)(src + idx);
  ushort4 o;
  o.x = f2bf(xv.x); o.y = f2bf(xv.y); o.z = f2bf(xv.z); o.w = f2bf(xv.w);
  *(ushort4*)(dst + idx) = o;
}

// ---------- transpose 4x 1024x1024 weight fp32 -> bf16 (Wt[n][k] = W[k][n]) ----------
__global__ __launch_bounds__(256) void transpose_all(const float* __restrict__ W0,
                                                     const float* __restrict__ W1,
                                                     const float* __restrict__ W2,
                                                     const float* __restrict__ W3,
                                                     unsigned short* __restrict__ T0,
                                                     unsigned short* __restrict__ T1,
                                                     unsigned short* __restrict__ T2,
                                                     unsigned short* __restrict__ T3) {
  __shared__ float t[64][68];
  int sel = blockIdx.x >> 8;
  const float* W = sel == 0 ? W0 : sel == 1 ? W1 : sel == 2 ? W2 : W3;
  unsigned short* Wt = sel == 0 ? T0 : sel == 1 ? T1 : sel == 2 ? T2 : T3;
  int tile = blockIdx.x & 255;
  int tr = tile >> 4, tc = tile & 15;
  int lr = threadIdx.x >> 4, lc4 = threadIdx.x & 15;
#pragma unroll
  for (int i = 0; i < 4; ++i) {
    int r = i * 16 + lr;
    float4 v = *(const float4*)(W + (size_t)(tr * 64 + r) * 1024 + tc * 64 + lc4 * 4);
    t[r][lc4 * 4 + 0] = v.x; t[r][lc4 * 4 + 1] = v.y;
    t[r][lc4 * 4 + 2] = v.z; t[r][lc4 * 4 + 3] = v.w;
  }
  __syncthreads();
#pragma unroll
  for (int i = 0; i < 4; ++i) {
    int r = i * 16 + lr;
    ushort4 o;
    o.x = f2bf(t[lc4 * 4 + 0][r]);
    o.y = f2bf(t[lc4 * 4 + 1][r]);
    o.z = f2bf(t[lc4 * 4 + 2][r]);
    o.w = f2bf(t[lc4 * 4 + 3][r]);
    *(ushort4*)(Wt + (size_t)(tc * 64 + r) * 1024 + tr * 64 + lc4 * 4) = o;
  }
}

// ---------- GEMM core: C[4096,1024] = A[4096,1024] @ Bt[1024,1024]^T + bias, *scale ----------
// mode 0: bf16 out, [B,H,S,64]; mode 1: bf16 out, [B,H,64,S]; mode 2: fp32 row-major
DEV void gemm_core(const unsigned short* __restrict__ A, const unsigned short* __restrict__ Bt,
                   const float* __restrict__ bias, void* __restrict__ Cout,
                   float scale, int mode, int blk,
                   unsigned short* As, unsigned short* Bs) {
  const int tid = threadIdx.x;
  const int l = tid & 63, w = tid >> 6;
  const int wm = w >> 1, wn = w & 1;
  const int r15 = l & 15, kg = l >> 4;
  const int mt = blk >> 3, nt = blk & 7;

  const f32x4 fz = {0.f, 0.f, 0.f, 0.f};
  f32x4 acc[4][4];
#pragma unroll
  for (int i = 0; i < 4; ++i)
#pragma unroll
    for (int j = 0; j < 4; ++j) acc[i][j] = fz;

  for (int kt = 0; kt < 16; ++kt) {
#pragma unroll
    for (int c = 0; c < 4; ++c) {
      int chunk = c * 256 + tid;
      int row = chunk >> 3, slot = chunk & 7;
      int gsl = slot ^ (row & 7);
      gload_lds16(A + (size_t)(mt * 128 + row) * 1024 + kt * 64 + gsl * 8, As + chunk * 8);
      gload_lds16(Bt + (size_t)(nt * 128 + row) * 1024 + kt * 64 + gsl * 8, Bs + chunk * 8);
    }
    __syncthreads();
#pragma unroll
    for (int ks = 0; ks < 2; ++ks) {
      bf16x8 a[4], b[4];
      int slot = ks * 4 + kg;
#pragma unroll
      for (int i = 0; i < 4; ++i) {
        int ra = wm * 64 + i * 16 + r15;
        a[i] = *(const bf16x8*)(As + ra * 64 + (slot ^ (ra & 7)) * 8);
        int rb = wn * 64 + i * 16 + r15;
        b[i] = *(const bf16x8*)(Bs + rb * 64 + (slot ^ (rb & 7)) * 8);
      }
#pragma unroll
      for (int i = 0; i < 4; ++i)
#pragma unroll
        for (int j = 0; j < 4; ++j)
          acc[i][j] = __builtin_amdgcn_mfma_f32_16x16x32_bf16(a[i], b[j], acc[i][j], 0, 0, 0);
    }
    __syncthreads();
  }

#pragma unroll
  for (int j = 0; j < 4; ++j) {
    int gc = nt * 128 + wn * 64 + j * 16 + r15;
    float bj = bias[gc];
#pragma unroll
    for (int i = 0; i < 4; ++i) {
#pragma unroll
      for (int r = 0; r < 4; ++r) {
        int gr = mt * 128 + wm * 64 + i * 16 + kg * 4 + r;
        float val = (acc[i][j][r] + bj) * scale;
        if (mode == 2) {
          ((float*)Cout)[(size_t)gr * 1024 + gc] = val;
        } else {
          int bb = gr >> 11, s = gr & 2047, hh = gc >> 6, dk = gc & 63;
          if (mode == 0)
            ((unsigned short*)Cout)[((size_t)(bb * 16 + hh) * 2048 + s) * 64 + dk] = f2bf(val);
          else
            ((unsigned short*)Cout)[((size_t)(bb * 16 + hh) * 64 + dk) * 2048 + s] = f2bf(val);
        }
      }
    }
  }
}

__global__ __launch_bounds__(256) void gemm_qkv(const unsigned short* __restrict__ qb,
                                                const unsigned short* __restrict__ kb,
                                                const unsigned short* __restrict__ vb,
                                                const unsigned short* __restrict__ Wtq,
                                                const unsigned short* __restrict__ Wtk,
                                                const unsigned short* __restrict__ Wtv,
                                                const float* __restrict__ bq,
                                                const float* __restrict__ bk,
                                                const float* __restrict__ bv,
                                                unsigned short* __restrict__ Qh,
                                                unsigned short* __restrict__ Kh,
                                                unsigned short* __restrict__ Vt) {
  __shared__ unsigned short As[128 * 64];
  __shared__ unsigned short Bs[128 * 64];
  int sel = blockIdx.x >> 8, blk = blockIdx.x & 255;
  const unsigned short* A = sel == 0 ? qb : sel == 1 ? kb : vb;
  const unsigned short* Bt = sel == 0 ? Wtq : sel == 1 ? Wtk : Wtv;
  const float* bias = sel == 0 ? bq : sel == 1 ? bk : bv;
  void* C = sel == 0 ? (void*)Qh : sel == 1 ? (void*)Kh : (void*)Vt;
  gemm_core(A, Bt, bias, C, sel == 0 ? 0.125f : 1.0f, sel == 2 ? 1 : 0, blk, As, Bs);
}

__global__ __launch_bounds__(256) void gemm_out(const unsigned short* __restrict__ AO,
                                                const unsigned short* __restrict__ Wto,
                                                const float* __restrict__ bo,
                                                float* __restrict__ out0) {
  __shared__ unsigned short As[128 * 64];
  __shared__ unsigned short Bs[128 * 64];
  gemm_core(AO, Wto, bo, out0, 1.0f, 2, blockIdx.x, As, Bs);
}

// ---------- attention: two-pass flash-style, 32 q-rows per wg ----------
// Pass A: online (m, sumexp) in registers via swapped QK^T (K supplies rows, Q cols).
// Pass B: recompute scores, write normalized attn (via 4KB Pbuf bounce, coalesced
// float4), accumulate PV transposed: out^T[d][q] = sum_k Vt[d][k] * P[q][k].
__global__ __launch_bounds__(256, 4) void attn_kernel(const unsigned short* __restrict__ Qh,
                                                      const unsigned short* __restrict__ Kh,
                                                      const unsigned short* __restrict__ Vt,
                                                      float* __restrict__ attnO,
                                                      unsigned short* __restrict__ AO) {
  __shared__ unsigned short Pbuf[2][32 * 64];
  __shared__ float Ms[4][32], Ss[4][32];
  __shared__ float mrow[32], rrow[32];

  const int tid = threadIdx.x;
  const int l = tid & 63, w = tid >> 6;
  const int r15 = l & 15, kg = l >> 4;

  // chunked XCD swizzle: each XCD gets 256 consecutive logical blocks (4 heads)
  const int lb = ((int)blockIdx.x & 7) * 256 + ((int)blockIdx.x >> 3);
  const int bh = lb >> 6;
  const int q0 = (lb & 63) * 32;
  const int b = bh >> 4, h = bh & 15;

  const unsigned short* Kbase = Kh + (size_t)bh * 2048 * 64;
  const unsigned short* Vbase = Vt + (size_t)bh * 64 * 2048;

  // Q fragments (Q pre-scaled 1/8): col-operand, lane r15 -> q row, kg -> dk chunk
  bf16x8 aq[2][2];
#pragma unroll
  for (int j = 0; j < 2; ++j)
#pragma unroll
    for (int h2 = 0; h2 < 2; ++h2)
      aq[j][h2] = *(const bf16x8*)(Qh + ((size_t)bh * 2048 + q0 + j * 16 + r15) * 64 +
                                   (h2 * 4 + kg) * 8);

  const int krow = w * 16 + r15;  // this lane's k-column (row-operand index)
  const f32x4 z4 = {0.f, 0.f, 0.f, 0.f};

  float m2[2] = {-3e38f, -3e38f}, s2[2] = {0.f, 0.f};

  // ---- pass A: per-row stats, no LDS, no barriers ----
  for (int kt = 0; kt < 32; ++kt) {
    const unsigned short* kp = Kbase + (size_t)(kt * 64 + krow) * 64;
    bf16x8 kf0 = *(const bf16x8*)(kp + kg * 8);
    bf16x8 kf1 = *(const bf16x8*)(kp + 32 + kg * 8);
#pragma unroll
    for (int j = 0; j < 2; ++j) {
      f32x4 sc = __builtin_amdgcn_mfma_f32_16x16x32_bf16(kf0, aq[j][0], z4, 0, 0, 0);
      sc = __builtin_amdgcn_mfma_f32_16x16x32_bf16(kf1, aq[j][1], sc, 0, 0, 0);
      float tm = fmaxf(fmaxf(sc[0], sc[1]), fmaxf(sc[2], sc[3]));
      float mn = fmaxf(m2[j], tm);
      s2[j] = s2[j] * __expf(m2[j] - mn) + __expf(sc[0] - mn) + __expf(sc[1] - mn) +
              __expf(sc[2] - mn) + __expf(sc[3] - mn);
      m2[j] = mn;
    }
  }

  // reduce over kg (lanes ^16, ^32), then across waves via LDS
#pragma unroll
  for (int j = 0; j < 2; ++j) {
#pragma unroll
    for (int off = 16; off <= 32; off <<= 1) {
      float mo = __shfl_xor(m2[j], off, 64);
      float so = __shfl_xor(s2[j], off, 64);
      float mn = fmaxf(m2[j], mo);
      s2[j] = s2[j] * __expf(m2[j] - mn) + so * __expf(mo - mn);
      m2[j] = mn;
    }
    if (kg == 0) { Ms[w][j * 16 + r15] = m2[j]; Ss[w][j * 16 + r15] = s2[j]; }
  }
  __syncthreads();
  if (tid < 32) {
    float m = Ms[0][tid], s = Ss[0][tid];
#pragma unroll
    for (int ww = 1; ww < 4; ++ww) {
      float mo = Ms[ww][tid], so = Ss[ww][tid];
      float mn = fmaxf(m, mo);
      s = s * __expf(m - mn) + so * __expf(mo - mn);
      m = mn;
    }
    mrow[tid] = m;
    rrow[tid] = 1.0f / s;
  }
  __syncthreads();

  const float mq[2] = {mrow[r15], mrow[16 + r15]};
  const float rvq[2] = {rrow[r15], rrow[16 + r15]};
  const int prow = tid >> 3;
  const int pc8 = (tid & 7) * 8;
  const float rv_w = rrow[prow];
  float* attnBase = attnO + ((size_t)bh * 2048 + q0) * 2048;

  f32x4 oacc[2] = {z4, z4};
  const unsigned short* vp = Vbase + (size_t)(w * 16 + r15) * 2048;  // lane's d-row

  // ---- pass B: recompute, write attn, PV ----
  for (int kt = 0; kt < 32; ++kt) {
    const unsigned short* kp = Kbase + (size_t)(kt * 64 + krow) * 64;
    bf16x8 kf0 = *(const bf16x8*)(kp + kg * 8);
    bf16x8 kf1 = *(const bf16x8*)(kp + 32 + kg * 8);
    unsigned short* Pb = &Pbuf[kt & 1][0];
#pragma unroll
    for (int j = 0; j < 2; ++j) {
      f32x4 sc = __builtin_amdgcn_mfma_f32_16x16x32_bf16(kf0, aq[j][0], z4, 0, 0, 0);
      sc = __builtin_amdgcn_mfma_f32_16x16x32_bf16(kf1, aq[j][1], sc, 0, 0, 0);
      ushort4 e;
      e.x = f2bf(__expf(sc[0] - mq[j]));
      e.y = f2bf(__expf(sc[1] - mq[j]));
      e.z = f2bf(__expf(sc[2] - mq[j]));
      e.w = f2bf(__expf(sc[3] - mq[j]));
      int q = j * 16 + r15;
      int c4 = (w * 4 + kg) ^ ((q & 7) << 1);  // 4-elem granule swizzle
      *(ushort4*)(Pb + q * 64 + c4 * 4) = e;
    }
    __syncthreads();
    // PV (transposed): rows = d from Vt, cols = q from Pbuf
    bf16x8 av0 = *(const bf16x8*)(vp + kt * 64 + kg * 8);
    bf16x8 av1 = *(const bf16x8*)(vp + kt * 64 + 32 + kg * 8);
#pragma unroll
    for (int j = 0; j < 2; ++j) {
      int q = j * 16 + r15;
      bf16x8 pf0 = *(const bf16x8*)(Pb + q * 64 + ((kg ^ (q & 7)) * 8));
      bf16x8 pf1 = *(const bf16x8*)(Pb + q * 64 + (((4 + kg) ^ (q & 7)) * 8));
      oacc[j] = __builtin_amdgcn_mfma_f32_16x16x32_bf16(av0, pf0, oacc[j], 0, 0, 0);
      oacc[j] = __builtin_amdgcn_mfma_f32_16x16x32_bf16(av1, pf1, oacc[j], 0, 0, 0);
    }
    // attn writeout: coalesced float4, normalized
    {
      bf16x8 pv = *(const bf16x8*)(Pb + prow * 64 + (((pc8 >> 3) ^ (prow & 7)) * 8));
      float4 o0, o1;
      o0.x = (float)pv[0] * rv_w; o0.y = (float)pv[1] * rv_w;
      o0.z = (float)pv[2] * rv_w; o0.w = (float)pv[3] * rv_w;
      o1.x = (float)pv[4] * rv_w; o1.y = (float)pv[5] * rv_w;
      o1.z = (float)pv[6] * rv_w; o1.w = (float)pv[7] * rv_w;
      float* dst = attnBase + (size_t)prow * 2048 + kt * 64 + pc8;
      *(float4*)dst = o0;
      *(float4*)(dst + 4) = o1;
    }
  }

  // epilogue: normalize PV accum, write AO[b, q, h*64+d] bf16
#pragma unroll
  for (int j = 0; j < 2; ++j) {
    float rv = rvq[j];
    ushort4 o;
    o.x = f2bf(oacc[j][0] * rv);
    o.y = f2bf(oacc[j][1] * rv);
    o.z = f2bf(oacc[j][2] * rv);
    o.w = f2bf(oacc[j][3] * rv);
    int q = q0 + j * 16 + r15;
    *(ushort4*)(AO + ((size_t)(b * 2048 + q)) * 1024 + h * 64 + w * 16 + kg * 4) = o;
  }
}

extern "C" void kernel_launch(void* const* d_in, const int* in_sizes, int n_in,
                              void* d_out, int out_size, void* d_ws, size_t ws_size,
                              hipStream_t stream) {
  const float* q  = (const float*)d_in[0];
  const float* k  = (const float*)d_in[1];
  const float* v  = (const float*)d_in[2];
  const float* Wq = (const float*)d_in[3];
  const float* bq = (const float*)d_in[4];
  const float* Wk = (const float*)d_in[5];
  const float* bk = (const float*)d_in[6];
  const float* Wv = (const float*)d_in[7];
  const float* bvp = (const float*)d_in[8];
  const float* Wo = (const float*)d_in[9];
  const float* bo = (const float*)d_in[10];

  char* wsb = (char*)d_ws;
  const size_t MB = (size_t)1 << 20;
  unsigned short* qb  = (unsigned short*)(wsb + 0 * MB);
  unsigned short* kbp = (unsigned short*)(wsb + 8 * MB);
  unsigned short* vbp = (unsigned short*)(wsb + 16 * MB);
  unsigned short* Wtq = (unsigned short*)(wsb + 24 * MB);
  unsigned short* Wtk = (unsigned short*)(wsb + 26 * MB);
  unsigned short* Wtv = (unsigned short*)(wsb + 28 * MB);
  unsigned short* Wto = (unsigned short*)(wsb + 30 * MB);
  unsigned short* Qh  = (unsigned short*)(wsb + 32 * MB);
  unsigned short* Kh  = (unsigned short*)(wsb + 40 * MB);
  unsigned short* Vt  = (unsigned short*)(wsb + 48 * MB);
  unsigned short* AO  = (unsigned short*)(wsb + 56 * MB);

  float* out0 = (float*)d_out;
  float* attnO = out0 + (size_t)2 * 2048 * 1024;

  cvt_qkv<<<dim3(4096, 3), 256, 0, stream>>>(q, k, v, qb, kbp, vbp);
  transpose_all<<<1024, 256, 0, stream>>>(Wq, Wk, Wv, Wo, Wtq, Wtk, Wtv, Wto);
  gemm_qkv<<<768, 256, 0, stream>>>(qb, kbp, vbp, Wtq, Wtk, Wtv, bq, bk, bvp, Qh, Kh, Vt);
  attn_kernel<<<2048, 256, 0, stream>>>(Qh, Kh, Vt, attnO, AO);
  gemm_out<<<256, 256, 0, stream>>>(AO, Wto, bo, (float*)d_out);
}